// Round 2
// baseline (1009.861 us; speedup 1.0000x reference)
//
#include <hip/hip_runtime.h>
#include <math.h>

#define NN 8192
#define NE 131072
#define NG 64
#define FIN 64
#define FE 32

static __device__ __forceinline__ float relu(float v){ return v > 0.f ? v : 0.f; }

static __device__ __forceinline__ float rdlane(float v, int l){
  return __int_as_float(__builtin_amdgcn_readlane(__float_as_int(v), l));
}

// ---------------- counting sorts (src and dst CSR) ----------------
__global__ void k_hist(const int* __restrict__ ei, int* scnt, int* dcnt){
  int e = blockIdx.x*256 + threadIdx.x;
  if (e < NE){ atomicAdd(&scnt[ei[e]],1); atomicAdd(&dcnt[ei[NE+e]],1); }
}

__global__ void k_scan(const int* __restrict__ scnt, const int* __restrict__ dcnt,
                       int* soff, int* scur, int* doff, int* dcur){
  const int* cnt = (blockIdx.x==0) ? scnt : dcnt;
  int* off = (blockIdx.x==0) ? soff : doff;
  int* cur = (blockIdx.x==0) ? scur : dcur;
  __shared__ int sums[1024];
  int t = threadIdx.x;
  int v[8]; int s = 0;
  #pragma unroll
  for (int j=0;j<8;++j){ v[j]=cnt[t*8+j]; s+=v[j]; }
  sums[t]=s; __syncthreads();
  for (int d=1; d<1024; d<<=1){
    int val = (t>=d) ? sums[t-d] : 0;
    __syncthreads();
    sums[t] += val;
    __syncthreads();
  }
  int run = sums[t]-s;   // exclusive prefix
  #pragma unroll
  for (int j=0;j<8;++j){ off[t*8+j]=run; cur[t*8+j]=run; run+=v[j]; }
  if (t==1023) off[NN]=run;
}

__global__ void k_scatter(const int* __restrict__ ei, int* scur, int* dcur,
                          int* sperm, int* dperm){
  int e = blockIdx.x*256 + threadIdx.x;
  if (e < NE){
    int s = ei[e], d = ei[NE+e];
    sperm[atomicAdd(&scur[s],1)] = e;
    dperm[atomicAdd(&dcur[d],1)] = e;
  }
}

// ---------------- EdgeMLP layers 1+2 fused: edge_attr -> h2 [E,64] ----------------
// Weights entirely in VGPRs; broadcasts via v_readlane (no LDS at all).
__global__ __launch_bounds__(256,2) void k_mlp12(const float* __restrict__ EA,
      const float* __restrict__ W1, const float* __restrict__ B1,
      const float* __restrict__ W2, const float* __restrict__ B2,
      float* __restrict__ H2out){
  int tid=threadIdx.x, wv=tid>>6, lane=tid&63;
  float w1a[32], w1b[32], w2r[128];
  #pragma unroll
  for (int i=0;i<32;++i){ w1a[i]=W1[i*128+lane]; w1b[i]=W1[i*128+64+lane]; }
  #pragma unroll
  for (int k=0;k<128;++k) w2r[k]=W2[k*64+lane];
  float b1a=B1[lane], b1b=B1[64+lane], b2v=B2[lane];

  #pragma unroll 1
  for (int t=0;t<8;++t){
    int e0 = blockIdx.x*128 + t*16 + wv*4;
    float r0 = EA[(size_t)e0*32 + lane];        // edges e0,e0+1 feats
    float r1 = EA[(size_t)e0*32 + 64 + lane];   // edges e0+2,e0+3 feats
    float a0[4], a1[4];
    #pragma unroll
    for (int e=0;e<4;++e){ a0[e]=b1a; a1[e]=b1b; }
    #pragma unroll
    for (int i=0;i<32;++i){
      #pragma unroll
      for (int e=0;e<4;++e){
        const int f = e*32+i;
        float sx = rdlane((f<64)?r0:r1, f&63);
        a0[e] += sx*w1a[i];
        a1[e] += sx*w1b[i];
      }
    }
    #pragma unroll
    for (int e=0;e<4;++e){ a0[e]=relu(a0[e]); a1[e]=relu(a1[e]); }
    float c[4];
    #pragma unroll
    for (int e=0;e<4;++e) c[e]=b2v;
    #pragma unroll
    for (int k=0;k<64;++k){
      #pragma unroll
      for (int e=0;e<4;++e) c[e] += rdlane(a0[e],k)*w2r[k];
    }
    #pragma unroll
    for (int k=0;k<64;++k){
      #pragma unroll
      for (int e=0;e<4;++e) c[e] += rdlane(a1[e],k)*w2r[64+k];
    }
    #pragma unroll
    for (int e=0;e<4;++e) H2out[(size_t)(e0+e)*64+lane] = relu(c[e]);
  }
}

// ---------------- P[n,k,o] = sum_i x[n,i] * W3[k, i*64+o] ----------------
// lane=o; x via readlane stash; W3 streamed coalesced from L2; acc in regs.
__global__ __launch_bounds__(512,4) void k_pgen(const float* __restrict__ X,
      const float* __restrict__ W3, float* __restrict__ P){
  int tid = threadIdx.x;
  int kk = tid>>6, lane = tid&63;
  int n0 = blockIdx.x*8;
  float xv[8];
  #pragma unroll
  for (int n=0;n<8;++n) xv[n] = X[(size_t)(n0+n)*64 + lane];
  float acc[8][8];
  #pragma unroll
  for (int n=0;n<8;++n)
    #pragma unroll
    for (int j=0;j<8;++j) acc[n][j]=0.f;
  const float* wb = W3 + (size_t)(kk*8)*4096 + lane;
  #pragma unroll 4
  for (int i=0;i<64;++i){
    float w[8];
    #pragma unroll
    for (int j=0;j<8;++j) w[j] = wb[(size_t)j*4096 + i*64];
    float sx[8];
    #pragma unroll
    for (int n=0;n<8;++n) sx[n] = rdlane(xv[n], i);
    #pragma unroll
    for (int n=0;n<8;++n)
      #pragma unroll
      for (int j=0;j<8;++j) acc[n][j] += sx[n]*w[j];
  }
  float* pb = P + (size_t)n0*4096 + (size_t)kk*8*64 + lane;
  #pragma unroll
  for (int n=0;n<8;++n)
    #pragma unroll
    for (int j=0;j<8;++j)
      pb[(size_t)n*4096 + j*64] = acc[n][j];
}

// ---------------- agg init = x @ root_w + conv1_b ; xb = x @ b3mat ----------------
__global__ __launch_bounds__(256) void k_root(const float* __restrict__ X,
      const float* __restrict__ RW, const float* __restrict__ CB,
      const float* __restrict__ B3, float* __restrict__ AGG, float* __restrict__ XB){
  int tid=threadIdx.x, wv=tid>>6, lane=tid&63;
  int n = blockIdx.x*4 + wv;
  float xr = X[(size_t)n*64+lane];
  float aA = CB[lane], aB = 0.f;
  #pragma unroll
  for (int i=0;i<64;++i){
    float sx = rdlane(xr, i);
    aA += sx*RW[i*64+lane];
    aB += sx*B3[i*64+lane];
  }
  AGG[(size_t)n*64+lane]=aA; XB[(size_t)n*64+lane]=aB;
}

// ---------------- msg[e] = h2[e] @ P[src] + xb[src]; scatter-add to agg[dst] ----------------
// P row in VGPRs; h broadcast via readlane; no LDS.
__global__ __launch_bounds__(64) void k_msg(const float* __restrict__ P,
      const float* __restrict__ H2v, const float* __restrict__ XB,
      const int* __restrict__ ei, const int* __restrict__ soff,
      const int* __restrict__ sperm, float* __restrict__ AGG){
  int lane = threadIdx.x;
  int n = blockIdx.x;
  int beg = soff[n], end = soff[n+1];
  if (beg==end) return;
  float pr[64];
  const float* pb = P + (size_t)n*4096 + lane;
  #pragma unroll
  for (int k=0;k<64;++k) pr[k] = pb[k*64];
  float xbv = XB[(size_t)n*64+lane];
  #pragma unroll 1
  for (int idx=beg; idx<end; ++idx){
    int e = sperm[idx];
    float h = H2v[(size_t)e*64+lane];
    int d = ei[NE+e];
    float acc = xbv;
    #pragma unroll
    for (int k=0;k<64;++k) acc += rdlane(h,k)*pr[k];
    atomicAdd(&AGG[(size_t)d*64+lane], acc);
  }
}

// ---------------- hg = relu(agg) @ gat_w ; per-node attn scalars ----------------
__global__ __launch_bounds__(256) void k_hg(const float* __restrict__ AGG,
      const float* __restrict__ GW, const float* __restrict__ ASRC,
      const float* __restrict__ ADST, float* __restrict__ HG,
      float* __restrict__ AS, float* __restrict__ AD){
  int tid=threadIdx.x, wv=tid>>6, lane=tid&63;
  int n = blockIdx.x*4+wv;
  float xr = relu(AGG[(size_t)n*64+lane]);
  float acc=0.f;
  #pragma unroll
  for (int i=0;i<64;++i){
    acc += rdlane(xr,i)*GW[i*64+lane];
  }
  HG[(size_t)n*64+lane]=acc;
  float t1 = acc*ASRC[lane], t2 = acc*ADST[lane];
  #pragma unroll
  for (int d=32; d>=1; d>>=1){ t1 += __shfl_xor(t1,d); t2 += __shfl_xor(t2,d); }
  if (lane==0){ AS[n]=t1; AD[n]=t2; }
}

// ---------------- GAT softmax + aggregate per dst node (incl self-loop) ----------------
__global__ __launch_bounds__(64) void k_gat(const float* __restrict__ HG,
      const float* __restrict__ AS, const float* __restrict__ AD,
      const float* __restrict__ GB, const int* __restrict__ ei,
      const int* __restrict__ doff, const int* __restrict__ dperm,
      float* __restrict__ X2){
  int lane = threadIdx.x;
  int n = blockIdx.x;
  int beg = doff[n], end = doff[n+1], deg = end-beg;
  float adn = AD[n];
  float selfsc = AS[n] + adn; selfsc = selfsc>0.f ? selfsc : 0.2f*selfsc;
  float lmax = -3.4e38f;
  for (int j=lane; j<deg; j+=64){
    int e = dperm[beg+j];
    float sc = AS[ei[e]] + adn; sc = sc>0.f ? sc : 0.2f*sc;
    lmax = fmaxf(lmax, sc);
  }
  #pragma unroll
  for (int d=32; d>=1; d>>=1) lmax = fmaxf(lmax, __shfl_xor(lmax,d));
  float mx = fmaxf(lmax, selfsc);
  float lsum = 0.f;
  for (int j=lane; j<deg; j+=64){
    int e = dperm[beg+j];
    float sc = AS[ei[e]] + adn; sc = sc>0.f ? sc : 0.2f*sc;
    lsum += expf(sc-mx);
  }
  #pragma unroll
  for (int d=32; d>=1; d>>=1) lsum += __shfl_xor(lsum,d);
  float wself = expf(selfsc-mx);
  float denom = lsum + wself;
  float acc = wself * HG[(size_t)n*64+lane];
  for (int idx=beg; idx<end; ++idx){
    int e = dperm[idx];
    int s = ei[e];
    float sc = AS[s] + adn; sc = sc>0.f ? sc : 0.2f*sc;
    float wgt = expf(sc-mx);
    acc += wgt * HG[(size_t)s*64+lane];
  }
  X2[(size_t)n*64+lane] = relu(acc/denom + GB[lane]);
}

// ---------------- mean-pool per graph + 3-layer MLP head ----------------
__global__ __launch_bounds__(64) void k_head(const float* __restrict__ X2,
      const int* __restrict__ batch,
      const float* __restrict__ F1W, const float* __restrict__ F1B,
      const float* __restrict__ F2W, const float* __restrict__ F2B,
      const float* __restrict__ F3W, const float* __restrict__ F3B,
      float* __restrict__ OUT){
  int lane = threadIdx.x;
  int g = blockIdx.x;
  int lo=0, hi=NN;
  while (lo<hi){ int m=(lo+hi)>>1; if (batch[m] < g) lo=m+1; else hi=m; }
  int start = lo;
  lo=0; hi=NN;
  while (lo<hi){ int m=(lo+hi)>>1; if (batch[m] < g+1) lo=m+1; else hi=m; }
  int stop = lo;
  float s = 0.f;
  for (int r=start; r<stop; ++r) s += X2[(size_t)r*64+lane];
  float cnt = (float)(stop-start);
  float mean = s / fmaxf(cnt, 1.f);
  float a0=F1B[lane], a1=F1B[64+lane];
  #pragma unroll
  for (int i=0;i<64;++i){
    float mv = rdlane(mean, i);
    a0 += mv*F1W[i*128+lane];
    a1 += mv*F1W[i*128+64+lane];
  }
  float g1a = relu(a0), g1b = relu(a1);
  float b = F2B[lane];
  #pragma unroll
  for (int k=0;k<64;++k){
    b += rdlane(g1a,k)*F2W[k*64+lane];
  }
  #pragma unroll
  for (int k=0;k<64;++k){
    b += rdlane(g1b,k)*F2W[(64+k)*64+lane];
  }
  float g2v = relu(b);
  float cc = (lane<32) ? F3B[lane] : 0.f;
  #pragma unroll
  for (int k=0;k<64;++k){
    cc += rdlane(g2v,k)*F3W[k*32+(lane&31)];
  }
  if (lane < 32) OUT[g*32+lane] = relu(cc);
}

extern "C" void kernel_launch(void* const* d_in, const int* in_sizes, int n_in,
                              void* d_out, int out_size, void* d_ws, size_t ws_size,
                              hipStream_t stream){
  const float* X   = (const float*)d_in[0];
  const float* EA  = (const float*)d_in[1];
  const float* W1  = (const float*)d_in[2];
  const float* B1  = (const float*)d_in[3];
  const float* W2  = (const float*)d_in[4];
  const float* B2  = (const float*)d_in[5];
  const float* W3  = (const float*)d_in[6];
  const float* B3  = (const float*)d_in[7];
  const float* RW  = (const float*)d_in[8];
  const float* CB  = (const float*)d_in[9];
  const float* GW  = (const float*)d_in[10];
  const float* ASRC= (const float*)d_in[11];
  const float* ADST= (const float*)d_in[12];
  const float* GB  = (const float*)d_in[13];
  const float* F1W = (const float*)d_in[14];
  const float* F1B = (const float*)d_in[15];
  const float* F2W = (const float*)d_in[16];
  const float* F2B = (const float*)d_in[17];
  const float* F3W = (const float*)d_in[18];
  const float* F3B = (const float*)d_in[19];
  const int*   EI  = (const int*)d_in[20];
  const int*   BATCH = (const int*)d_in[21];
  float* OUT = (float*)d_out;
  (void)in_sizes; (void)n_in; (void)out_size; (void)ws_size;

  char* w = (char*)d_ws;
  size_t off = 0;
  auto alloc = [&](size_t bytes)->char*{
    char* p = w + off; off = (off + bytes + 255) & ~(size_t)255; return p;
  };
  float* P    = (float*)alloc((size_t)NN*4096*4);   // 134 MB
  float* H2v  = (float*)alloc((size_t)NE*64*4);     // 33.5 MB
  float* XB   = (float*)alloc((size_t)NN*64*4);
  float* AGG  = (float*)alloc((size_t)NN*64*4);
  float* HGv  = (float*)alloc((size_t)NN*64*4);
  float* X2   = (float*)alloc((size_t)NN*64*4);
  float* AS   = (float*)alloc((size_t)NN*4);
  float* AD   = (float*)alloc((size_t)NN*4);
  int* scnt = (int*)alloc((size_t)NN*4);
  int* dcnt = (int*)alloc((size_t)NN*4);
  int* soff = (int*)alloc((size_t)(NN+1)*4);
  int* doff = (int*)alloc((size_t)(NN+1)*4);
  int* scur = (int*)alloc((size_t)NN*4);
  int* dcur = (int*)alloc((size_t)NN*4);
  int* sperm= (int*)alloc((size_t)NE*4);
  int* dperm= (int*)alloc((size_t)NE*4);

  hipMemsetAsync(scnt, 0, NN*4, stream);
  hipMemsetAsync(dcnt, 0, NN*4, stream);
  k_hist<<<NE/256,256,0,stream>>>(EI, scnt, dcnt);
  k_scan<<<2,1024,0,stream>>>(scnt,dcnt,soff,scur,doff,dcur);
  k_scatter<<<NE/256,256,0,stream>>>(EI,scur,dcur,sperm,dperm);
  k_mlp12<<<NE/128,256,0,stream>>>(EA,W1,B1,W2,B2,H2v);
  k_pgen<<<NN/8,512,0,stream>>>(X,W3,P);
  k_root<<<NN/4,256,0,stream>>>(X,RW,CB,B3,AGG,XB);
  k_msg<<<NN,64,0,stream>>>(P,H2v,XB,EI,soff,sperm,AGG);
  k_hg<<<NN/4,256,0,stream>>>(AGG,GW,ASRC,ADST,HGv,AS,AD);
  k_gat<<<NN,64,0,stream>>>(HGv,AS,AD,GB,EI,doff,dperm,X2);
  k_head<<<NG,64,0,stream>>>(X2,BATCH,F1W,F1B,F2W,F2B,F3W,F3B,OUT);
}

// Round 3
// 651.364 us; speedup vs baseline: 1.5504x; 1.5504x over previous
//
#include <hip/hip_runtime.h>
#include <math.h>

#define NN 8192
#define NE 131072
#define NG 64
#define FIN 64
#define FE 32

static __device__ __forceinline__ float relu(float v){ return v > 0.f ? v : 0.f; }

static __device__ __forceinline__ float rdlane(float v, int l){
  return __int_as_float(__builtin_amdgcn_readlane(__float_as_int(v), l));
}

// ---------------- counting sorts (src and dst CSR) ----------------
__global__ void k_hist(const int* __restrict__ ei, int* scnt, int* dcnt){
  int e = blockIdx.x*256 + threadIdx.x;
  if (e < NE){ atomicAdd(&scnt[ei[e]],1); atomicAdd(&dcnt[ei[NE+e]],1); }
}

__global__ void k_scan(const int* __restrict__ scnt, const int* __restrict__ dcnt,
                       int* soff, int* scur, int* doff, int* dcur){
  const int* cnt = (blockIdx.x==0) ? scnt : dcnt;
  int* off = (blockIdx.x==0) ? soff : doff;
  int* cur = (blockIdx.x==0) ? scur : dcur;
  __shared__ int sums[1024];
  int t = threadIdx.x;
  int v[8]; int s = 0;
  #pragma unroll
  for (int j=0;j<8;++j){ v[j]=cnt[t*8+j]; s+=v[j]; }
  sums[t]=s; __syncthreads();
  for (int d=1; d<1024; d<<=1){
    int val = (t>=d) ? sums[t-d] : 0;
    __syncthreads();
    sums[t] += val;
    __syncthreads();
  }
  int run = sums[t]-s;   // exclusive prefix
  #pragma unroll
  for (int j=0;j<8;++j){ off[t*8+j]=run; cur[t*8+j]=run; run+=v[j]; }
  if (t==1023) off[NN]=run;
}

__global__ void k_scatter(const int* __restrict__ ei, int* scur, int* dcur,
                          int* sperm, int* dperm){
  int e = blockIdx.x*256 + threadIdx.x;
  if (e < NE){
    int s = ei[e], d = ei[NE+e];
    sperm[atomicAdd(&scur[s],1)] = e;
    dperm[atomicAdd(&dcur[d],1)] = e;
  }
}

// ---------------- EdgeMLP layers 1+2 fused: edge_attr -> h2 [E,64] ----------------
// lane = edge. All weight indices wave-uniform -> scalar loads (s_load) feeding
// v_fmac's SGPR operand. No LDS, no broadcasts, no big register arrays.
__global__ __launch_bounds__(256,3) void k_mlp12(const float* __restrict__ EA,
      const float* __restrict__ W1, const float* __restrict__ B1,
      const float* __restrict__ W2, const float* __restrict__ B2,
      float* __restrict__ H2out){
  int tid=threadIdx.x, wv=tid>>6, lane=tid&63;
  int e = blockIdx.x*256 + wv*64 + lane;
  float ea[32];
  const float4* eap = (const float4*)(EA + (size_t)e*32);
  #pragma unroll
  for (int q=0;q<8;++q){
    float4 v = eap[q];
    ea[4*q+0]=v.x; ea[4*q+1]=v.y; ea[4*q+2]=v.z; ea[4*q+3]=v.w;
  }
  float h2a[64];
  #pragma unroll
  for (int o=0;o<64;++o) h2a[o]=B2[o];
  #pragma unroll 1
  for (int c=0;c<8;++c){
    float h1[16];
    #pragma unroll
    for (int j=0;j<16;++j){
      float a = B1[c*16+j];
      #pragma unroll
      for (int i=0;i<32;++i) a += ea[i]*W1[i*128 + c*16 + j];
      h1[j] = relu(a);
    }
    #pragma unroll
    for (int j=0;j<16;++j){
      #pragma unroll
      for (int o=0;o<64;++o) h2a[o] += h1[j]*W2[(c*16+j)*64 + o];
    }
  }
  float4* hp = (float4*)(H2out + (size_t)e*64);
  #pragma unroll
  for (int q=0;q<16;++q){
    hp[q] = make_float4(relu(h2a[4*q+0]), relu(h2a[4*q+1]),
                        relu(h2a[4*q+2]), relu(h2a[4*q+3]));
  }
}

// ---------------- P[n,k,o] = sum_i x[n,i] * W3[k, i*64+o] ----------------
// lane=o; x via readlane stash; W3 streamed coalesced from L2; acc in regs.
__global__ __launch_bounds__(512,4) void k_pgen(const float* __restrict__ X,
      const float* __restrict__ W3, float* __restrict__ P){
  int tid = threadIdx.x;
  int kk = tid>>6, lane = tid&63;
  int n0 = blockIdx.x*8;
  float xv[8];
  #pragma unroll
  for (int n=0;n<8;++n) xv[n] = X[(size_t)(n0+n)*64 + lane];
  float acc[8][8];
  #pragma unroll
  for (int n=0;n<8;++n)
    #pragma unroll
    for (int j=0;j<8;++j) acc[n][j]=0.f;
  const float* wb = W3 + (size_t)(kk*8)*4096 + lane;
  #pragma unroll 4
  for (int i=0;i<64;++i){
    float w[8];
    #pragma unroll
    for (int j=0;j<8;++j) w[j] = wb[(size_t)j*4096 + i*64];
    float sx[8];
    #pragma unroll
    for (int n=0;n<8;++n) sx[n] = rdlane(xv[n], i);
    #pragma unroll
    for (int n=0;n<8;++n)
      #pragma unroll
      for (int j=0;j<8;++j) acc[n][j] += sx[n]*w[j];
  }
  float* pb = P + (size_t)n0*4096 + (size_t)kk*8*64 + lane;
  #pragma unroll
  for (int n=0;n<8;++n)
    #pragma unroll
    for (int j=0;j<8;++j)
      pb[(size_t)n*4096 + j*64] = acc[n][j];
}

// ---------------- agg init = x @ root_w + conv1_b ; xb = x @ b3mat ----------------
__global__ __launch_bounds__(256) void k_root(const float* __restrict__ X,
      const float* __restrict__ RW, const float* __restrict__ CB,
      const float* __restrict__ B3, float* __restrict__ AGG, float* __restrict__ XB){
  int tid=threadIdx.x, wv=tid>>6, lane=tid&63;
  int n = blockIdx.x*4 + wv;
  float xr = X[(size_t)n*64+lane];
  float aA = CB[lane], aB = 0.f;
  #pragma unroll
  for (int i=0;i<64;++i){
    float sx = rdlane(xr, i);
    aA += sx*RW[i*64+lane];
    aB += sx*B3[i*64+lane];
  }
  AGG[(size_t)n*64+lane]=aA; XB[(size_t)n*64+lane]=aB;
}

// ---------------- msg[e] = h2[e] @ P[src] + xb[src]; scatter-add to agg[dst] ----------------
// P row in VGPRs; h broadcast via readlane; no LDS.
__global__ __launch_bounds__(64) void k_msg(const float* __restrict__ P,
      const float* __restrict__ H2v, const float* __restrict__ XB,
      const int* __restrict__ ei, const int* __restrict__ soff,
      const int* __restrict__ sperm, float* __restrict__ AGG){
  int lane = threadIdx.x;
  int n = blockIdx.x;
  int beg = soff[n], end = soff[n+1];
  if (beg==end) return;
  float pr[64];
  const float* pb = P + (size_t)n*4096 + lane;
  #pragma unroll
  for (int k=0;k<64;++k) pr[k] = pb[k*64];
  float xbv = XB[(size_t)n*64+lane];
  #pragma unroll 1
  for (int idx=beg; idx<end; ++idx){
    int e = sperm[idx];
    float h = H2v[(size_t)e*64+lane];
    int d = ei[NE+e];
    float acc = xbv;
    #pragma unroll
    for (int k=0;k<64;++k) acc += rdlane(h,k)*pr[k];
    atomicAdd(&AGG[(size_t)d*64+lane], acc);
  }
}

// ---------------- hg = relu(agg) @ gat_w ; per-node attn scalars ----------------
__global__ __launch_bounds__(256) void k_hg(const float* __restrict__ AGG,
      const float* __restrict__ GW, const float* __restrict__ ASRC,
      const float* __restrict__ ADST, float* __restrict__ HG,
      float* __restrict__ AS, float* __restrict__ AD){
  int tid=threadIdx.x, wv=tid>>6, lane=tid&63;
  int n = blockIdx.x*4+wv;
  float xr = relu(AGG[(size_t)n*64+lane]);
  float acc=0.f;
  #pragma unroll
  for (int i=0;i<64;++i){
    acc += rdlane(xr,i)*GW[i*64+lane];
  }
  HG[(size_t)n*64+lane]=acc;
  float t1 = acc*ASRC[lane], t2 = acc*ADST[lane];
  #pragma unroll
  for (int d=32; d>=1; d>>=1){ t1 += __shfl_xor(t1,d); t2 += __shfl_xor(t2,d); }
  if (lane==0){ AS[n]=t1; AD[n]=t2; }
}

// ---------------- GAT softmax + aggregate per dst node (incl self-loop) ----------------
__global__ __launch_bounds__(64) void k_gat(const float* __restrict__ HG,
      const float* __restrict__ AS, const float* __restrict__ AD,
      const float* __restrict__ GB, const int* __restrict__ ei,
      const int* __restrict__ doff, const int* __restrict__ dperm,
      float* __restrict__ X2){
  int lane = threadIdx.x;
  int n = blockIdx.x;
  int beg = doff[n], end = doff[n+1], deg = end-beg;
  float adn = AD[n];
  float selfsc = AS[n] + adn; selfsc = selfsc>0.f ? selfsc : 0.2f*selfsc;
  float lmax = -3.4e38f;
  for (int j=lane; j<deg; j+=64){
    int e = dperm[beg+j];
    float sc = AS[ei[e]] + adn; sc = sc>0.f ? sc : 0.2f*sc;
    lmax = fmaxf(lmax, sc);
  }
  #pragma unroll
  for (int d=32; d>=1; d>>=1) lmax = fmaxf(lmax, __shfl_xor(lmax,d));
  float mx = fmaxf(lmax, selfsc);
  float lsum = 0.f;
  for (int j=lane; j<deg; j+=64){
    int e = dperm[beg+j];
    float sc = AS[ei[e]] + adn; sc = sc>0.f ? sc : 0.2f*sc;
    lsum += expf(sc-mx);
  }
  #pragma unroll
  for (int d=32; d>=1; d>>=1) lsum += __shfl_xor(lsum,d);
  float wself = expf(selfsc-mx);
  float denom = lsum + wself;
  float acc = wself * HG[(size_t)n*64+lane];
  for (int idx=beg; idx<end; ++idx){
    int e = dperm[idx];
    int s = ei[e];
    float sc = AS[s] + adn; sc = sc>0.f ? sc : 0.2f*sc;
    float wgt = expf(sc-mx);
    acc += wgt * HG[(size_t)s*64+lane];
  }
  X2[(size_t)n*64+lane] = relu(acc/denom + GB[lane]);
}

// ---------------- mean-pool per graph + 3-layer MLP head ----------------
__global__ __launch_bounds__(64) void k_head(const float* __restrict__ X2,
      const int* __restrict__ batch,
      const float* __restrict__ F1W, const float* __restrict__ F1B,
      const float* __restrict__ F2W, const float* __restrict__ F2B,
      const float* __restrict__ F3W, const float* __restrict__ F3B,
      float* __restrict__ OUT){
  int lane = threadIdx.x;
  int g = blockIdx.x;
  int lo=0, hi=NN;
  while (lo<hi){ int m=(lo+hi)>>1; if (batch[m] < g) lo=m+1; else hi=m; }
  int start = lo;
  lo=0; hi=NN;
  while (lo<hi){ int m=(lo+hi)>>1; if (batch[m] < g+1) lo=m+1; else hi=m; }
  int stop = lo;
  float s = 0.f;
  for (int r=start; r<stop; ++r) s += X2[(size_t)r*64+lane];
  float cnt = (float)(stop-start);
  float mean = s / fmaxf(cnt, 1.f);
  float a0=F1B[lane], a1=F1B[64+lane];
  #pragma unroll
  for (int i=0;i<64;++i){
    float mv = rdlane(mean, i);
    a0 += mv*F1W[i*128+lane];
    a1 += mv*F1W[i*128+64+lane];
  }
  float g1a = relu(a0), g1b = relu(a1);
  float b = F2B[lane];
  #pragma unroll
  for (int k=0;k<64;++k){
    b += rdlane(g1a,k)*F2W[k*64+lane];
  }
  #pragma unroll
  for (int k=0;k<64;++k){
    b += rdlane(g1b,k)*F2W[(64+k)*64+lane];
  }
  float g2v = relu(b);
  float cc = (lane<32) ? F3B[lane] : 0.f;
  #pragma unroll
  for (int k=0;k<64;++k){
    cc += rdlane(g2v,k)*F3W[k*32+(lane&31)];
  }
  if (lane < 32) OUT[g*32+lane] = relu(cc);
}

extern "C" void kernel_launch(void* const* d_in, const int* in_sizes, int n_in,
                              void* d_out, int out_size, void* d_ws, size_t ws_size,
                              hipStream_t stream){
  const float* X   = (const float*)d_in[0];
  const float* EA  = (const float*)d_in[1];
  const float* W1  = (const float*)d_in[2];
  const float* B1  = (const float*)d_in[3];
  const float* W2  = (const float*)d_in[4];
  const float* B2  = (const float*)d_in[5];
  const float* W3  = (const float*)d_in[6];
  const float* B3  = (const float*)d_in[7];
  const float* RW  = (const float*)d_in[8];
  const float* CB  = (const float*)d_in[9];
  const float* GW  = (const float*)d_in[10];
  const float* ASRC= (const float*)d_in[11];
  const float* ADST= (const float*)d_in[12];
  const float* GB  = (const float*)d_in[13];
  const float* F1W = (const float*)d_in[14];
  const float* F1B = (const float*)d_in[15];
  const float* F2W = (const float*)d_in[16];
  const float* F2B = (const float*)d_in[17];
  const float* F3W = (const float*)d_in[18];
  const float* F3B = (const float*)d_in[19];
  const int*   EI  = (const int*)d_in[20];
  const int*   BATCH = (const int*)d_in[21];
  float* OUT = (float*)d_out;
  (void)in_sizes; (void)n_in; (void)out_size; (void)ws_size;

  char* w = (char*)d_ws;
  size_t off = 0;
  auto alloc = [&](size_t bytes)->char*{
    char* p = w + off; off = (off + bytes + 255) & ~(size_t)255; return p;
  };
  float* P    = (float*)alloc((size_t)NN*4096*4);   // 134 MB
  float* H2v  = (float*)alloc((size_t)NE*64*4);     // 33.5 MB
  float* XB   = (float*)alloc((size_t)NN*64*4);
  float* AGG  = (float*)alloc((size_t)NN*64*4);
  float* HGv  = (float*)alloc((size_t)NN*64*4);
  float* X2   = (float*)alloc((size_t)NN*64*4);
  float* AS   = (float*)alloc((size_t)NN*4);
  float* AD   = (float*)alloc((size_t)NN*4);
  int* scnt = (int*)alloc((size_t)NN*4);
  int* dcnt = (int*)alloc((size_t)NN*4);
  int* soff = (int*)alloc((size_t)(NN+1)*4);
  int* doff = (int*)alloc((size_t)(NN+1)*4);
  int* scur = (int*)alloc((size_t)NN*4);
  int* dcur = (int*)alloc((size_t)NN*4);
  int* sperm= (int*)alloc((size_t)NE*4);
  int* dperm= (int*)alloc((size_t)NE*4);

  hipMemsetAsync(scnt, 0, NN*4, stream);
  hipMemsetAsync(dcnt, 0, NN*4, stream);
  k_hist<<<NE/256,256,0,stream>>>(EI, scnt, dcnt);
  k_scan<<<2,1024,0,stream>>>(scnt,dcnt,soff,scur,doff,dcur);
  k_scatter<<<NE/256,256,0,stream>>>(EI,scur,dcur,sperm,dperm);
  k_mlp12<<<NE/256,256,0,stream>>>(EA,W1,B1,W2,B2,H2v);
  k_pgen<<<NN/8,512,0,stream>>>(X,W3,P);
  k_root<<<NN/4,256,0,stream>>>(X,RW,CB,B3,AGG,XB);
  k_msg<<<NN,64,0,stream>>>(P,H2v,XB,EI,soff,sperm,AGG);
  k_hg<<<NN/4,256,0,stream>>>(AGG,GW,ASRC,ADST,HGv,AS,AD);
  k_gat<<<NN,64,0,stream>>>(HGv,AS,AD,GB,EI,doff,dperm,X2);
  k_head<<<NG,64,0,stream>>>(X2,BATCH,F1W,F1B,F2W,F2B,F3W,F3B,OUT);
}

// Round 7
// 503.014 us; speedup vs baseline: 2.0076x; 1.2949x over previous
//
#include <hip/hip_runtime.h>
#include <math.h>

#define NN 8192
#define NE 131072
#define NG 64
#define FIN 64
#define FE 32

static __device__ __forceinline__ float relu(float v){ return v > 0.f ? v : 0.f; }

static __device__ __forceinline__ float rdlane(float v, int l){
  return __int_as_float(__builtin_amdgcn_readlane(__float_as_int(v), l));
}

// ---------------- counting sorts (src and dst CSR) ----------------
__global__ void k_hist(const int* __restrict__ ei, int* scnt, int* dcnt){
  int e = blockIdx.x*256 + threadIdx.x;
  if (e < NE){ atomicAdd(&scnt[ei[e]],1); atomicAdd(&dcnt[ei[NE+e]],1); }
}

__global__ void k_scan(const int* __restrict__ scnt, const int* __restrict__ dcnt,
                       int* soff, int* scur, int* doff, int* dcur){
  const int* cnt = (blockIdx.x==0) ? scnt : dcnt;
  int* off = (blockIdx.x==0) ? soff : doff;
  int* cur = (blockIdx.x==0) ? scur : dcur;
  __shared__ int sums[1024];
  int t = threadIdx.x;
  int v[8]; int s = 0;
  #pragma unroll
  for (int j=0;j<8;++j){ v[j]=cnt[t*8+j]; s+=v[j]; }
  sums[t]=s; __syncthreads();
  for (int d=1; d<1024; d<<=1){
    int val = (t>=d) ? sums[t-d] : 0;
    __syncthreads();
    sums[t] += val;
    __syncthreads();
  }
  int run = sums[t]-s;   // exclusive prefix
  #pragma unroll
  for (int j=0;j<8;++j){ off[t*8+j]=run; cur[t*8+j]=run; run+=v[j]; }
  if (t==1023) off[NN]=run;
}

__global__ void k_scatter(const int* __restrict__ ei, int* scur, int* dcur,
                          int* sperm, int* dperm){
  int e = blockIdx.x*256 + threadIdx.x;
  if (e < NE){
    int s = ei[e], d = ei[NE+e];
    sperm[atomicAdd(&scur[s],1)] = e;
    dperm[atomicAdd(&dcur[d],1)] = e;
  }
}

// ---------------- EdgeMLP layer 1: H1 = relu(EA @ W1 + b1)  [E,128] ----------------
// lane owns outputs (lane, lane+64); W1 column pair in 64 VGPRs for whole kernel.
// 8 edges per iter; edge features stashed 4 regs/lane, broadcast via readlane (imm).
__global__ __launch_bounds__(256,2) void k_mlp1(const float* __restrict__ EA,
      const float* __restrict__ W1, const float* __restrict__ B1,
      float* __restrict__ H1out){
  int tid=threadIdx.x, wv=tid>>6, lane=tid&63;
  float w1a[32], w1b[32];
  #pragma unroll
  for (int i=0;i<32;++i){ w1a[i]=W1[i*128+lane]; w1b[i]=W1[i*128+64+lane]; }
  float b1a=B1[lane], b1b=B1[64+lane];
  int base = (blockIdx.x*4 + wv)*32;
  #pragma unroll 1
  for (int t=0;t<4;++t){
    int e0 = base + t*8;
    float r[4];
    #pragma unroll
    for (int q=0;q<4;++q) r[q] = EA[(size_t)e0*32 + q*64 + lane];
    float acc0[8], acc1[8];
    #pragma unroll
    for (int e=0;e<8;++e){ acc0[e]=b1a; acc1[e]=b1b; }
    #pragma unroll
    for (int i=0;i<32;++i){
      #pragma unroll
      for (int e=0;e<8;++e){
        float sx = rdlane(r[e>>1], (e&1)*32 + i);
        acc0[e] += sx*w1a[i];
        acc1[e] += sx*w1b[i];
      }
    }
    #pragma unroll
    for (int e=0;e<8;++e){
      H1out[(size_t)(e0+e)*128 + lane]      = relu(acc0[e]);
      H1out[(size_t)(e0+e)*128 + 64 + lane] = relu(acc1[e]);
    }
  }
}

// ---------------- EdgeMLP layer 2: H2 = relu(H1 @ W2 + b2)  [E,64] ----------------
// lane = output o. 16 edges per iter: h1 stash 32 regs; W2 streamed one coalesced
// row per k (L2-resident 32 KB). acc[16]. All array indices compile-time.
__global__ __launch_bounds__(256,2) void k_mlp2(const float* __restrict__ H1v,
      const float* __restrict__ W2, const float* __restrict__ B2,
      float* __restrict__ H2out){
  int tid=threadIdx.x, wv=tid>>6, lane=tid&63;
  float b2v = B2[lane];
  int base = (blockIdx.x*4 + wv)*32;
  #pragma unroll 1
  for (int t=0;t<2;++t){
    int e0 = base + t*16;
    float h[32];
    #pragma unroll
    for (int q=0;q<32;++q) h[q] = H1v[(size_t)e0*128 + q*64 + lane];
    float acc[16];
    #pragma unroll
    for (int e=0;e<16;++e) acc[e]=b2v;
    #pragma unroll
    for (int kh=0;kh<2;++kh){
      #pragma unroll 4
      for (int k2=0;k2<64;++k2){
        float w2v = W2[(kh*64+k2)*64 + lane];
        #pragma unroll
        for (int e=0;e<16;++e){
          acc[e] += rdlane(h[e*2+kh], k2) * w2v;
        }
      }
    }
    #pragma unroll
    for (int e=0;e<16;++e)
      H2out[(size_t)(e0+e)*64 + lane] = relu(acc[e]);
  }
}

// ---------------- P[n,k,o] = sum_i x[n,i] * W3[k, i*64+o] ----------------
// lane=o; x via readlane stash; W3 streamed coalesced from L2; acc in regs.
__global__ __launch_bounds__(512,4) void k_pgen(const float* __restrict__ X,
      const float* __restrict__ W3, float* __restrict__ P){
  int tid = threadIdx.x;
  int kk = tid>>6, lane = tid&63;
  int n0 = blockIdx.x*8;
  float xv[8];
  #pragma unroll
  for (int n=0;n<8;++n) xv[n] = X[(size_t)(n0+n)*64 + lane];
  float acc[8][8];
  #pragma unroll
  for (int n=0;n<8;++n)
    #pragma unroll
    for (int j=0;j<8;++j) acc[n][j]=0.f;
  const float* wb = W3 + (size_t)(kk*8)*4096 + lane;
  #pragma unroll 4
  for (int i=0;i<64;++i){
    float w[8];
    #pragma unroll
    for (int j=0;j<8;++j) w[j] = wb[(size_t)j*4096 + i*64];
    float sx[8];
    #pragma unroll
    for (int n=0;n<8;++n) sx[n] = rdlane(xv[n], i);
    #pragma unroll
    for (int n=0;n<8;++n)
      #pragma unroll
      for (int j=0;j<8;++j) acc[n][j] += sx[n]*w[j];
  }
  float* pb = P + (size_t)n0*4096 + (size_t)kk*8*64 + lane;
  #pragma unroll
  for (int n=0;n<8;++n)
    #pragma unroll
    for (int j=0;j<8;++j)
      pb[(size_t)n*4096 + j*64] = acc[n][j];
}

// ---------------- agg init = x @ root_w + conv1_b ; xb = x @ b3mat ----------------
__global__ __launch_bounds__(256) void k_root(const float* __restrict__ X,
      const float* __restrict__ RW, const float* __restrict__ CB,
      const float* __restrict__ B3, float* __restrict__ AGG, float* __restrict__ XB){
  int tid=threadIdx.x, wv=tid>>6, lane=tid&63;
  int n = blockIdx.x*4 + wv;
  float xr = X[(size_t)n*64+lane];
  float aA = CB[lane], aB = 0.f;
  #pragma unroll
  for (int i=0;i<64;++i){
    float sx = rdlane(xr, i);
    aA += sx*RW[i*64+lane];
    aB += sx*B3[i*64+lane];
  }
  AGG[(size_t)n*64+lane]=aA; XB[(size_t)n*64+lane]=aB;
}

// ---------------- msg[e] = h2[e] @ P[src] + xb[src]; scatter-add to agg[dst] ----------------
// P row in VGPRs; h broadcast via readlane; no LDS.
__global__ __launch_bounds__(64) void k_msg(const float* __restrict__ P,
      const float* __restrict__ H2v, const float* __restrict__ XB,
      const int* __restrict__ ei, const int* __restrict__ soff,
      const int* __restrict__ sperm, float* __restrict__ AGG){
  int lane = threadIdx.x;
  int n = blockIdx.x;
  int beg = soff[n], end = soff[n+1];
  if (beg==end) return;
  float pr[64];
  const float* pb = P + (size_t)n*4096 + lane;
  #pragma unroll
  for (int k=0;k<64;++k) pr[k] = pb[k*64];
  float xbv = XB[(size_t)n*64+lane];
  #pragma unroll 1
  for (int idx=beg; idx<end; ++idx){
    int e = sperm[idx];
    float h = H2v[(size_t)e*64+lane];
    int d = ei[NE+e];
    float acc = xbv;
    #pragma unroll
    for (int k=0;k<64;++k) acc += rdlane(h,k)*pr[k];
    atomicAdd(&AGG[(size_t)d*64+lane], acc);
  }
}

// ---------------- hg = relu(agg) @ gat_w ; per-node attn scalars ----------------
__global__ __launch_bounds__(256) void k_hg(const float* __restrict__ AGG,
      const float* __restrict__ GW, const float* __restrict__ ASRC,
      const float* __restrict__ ADST, float* __restrict__ HG,
      float* __restrict__ AS, float* __restrict__ AD){
  int tid=threadIdx.x, wv=tid>>6, lane=tid&63;
  int n = blockIdx.x*4+wv;
  float xr = relu(AGG[(size_t)n*64+lane]);
  float acc=0.f;
  #pragma unroll
  for (int i=0;i<64;++i){
    acc += rdlane(xr,i)*GW[i*64+lane];
  }
  HG[(size_t)n*64+lane]=acc;
  float t1 = acc*ASRC[lane], t2 = acc*ADST[lane];
  #pragma unroll
  for (int d=32; d>=1; d>>=1){ t1 += __shfl_xor(t1,d); t2 += __shfl_xor(t2,d); }
  if (lane==0){ AS[n]=t1; AD[n]=t2; }
}

// ---------------- GAT softmax + aggregate per dst node (incl self-loop) ----------------
__global__ __launch_bounds__(64) void k_gat(const float* __restrict__ HG,
      const float* __restrict__ AS, const float* __restrict__ AD,
      const float* __restrict__ GB, const int* __restrict__ ei,
      const int* __restrict__ doff, const int* __restrict__ dperm,
      float* __restrict__ X2){
  int lane = threadIdx.x;
  int n = blockIdx.x;
  int beg = doff[n], end = doff[n+1], deg = end-beg;
  float adn = AD[n];
  float selfsc = AS[n] + adn; selfsc = selfsc>0.f ? selfsc : 0.2f*selfsc;
  float lmax = -3.4e38f;
  for (int j=lane; j<deg; j+=64){
    int e = dperm[beg+j];
    float sc = AS[ei[e]] + adn; sc = sc>0.f ? sc : 0.2f*sc;
    lmax = fmaxf(lmax, sc);
  }
  #pragma unroll
  for (int d=32; d>=1; d>>=1) lmax = fmaxf(lmax, __shfl_xor(lmax,d));
  float mx = fmaxf(lmax, selfsc);
  float lsum = 0.f;
  for (int j=lane; j<deg; j+=64){
    int e = dperm[beg+j];
    float sc = AS[ei[e]] + adn; sc = sc>0.f ? sc : 0.2f*sc;
    lsum += expf(sc-mx);
  }
  #pragma unroll
  for (int d=32; d>=1; d>>=1) lsum += __shfl_xor(lsum,d);
  float wself = expf(selfsc-mx);
  float denom = lsum + wself;
  float acc = wself * HG[(size_t)n*64+lane];
  for (int idx=beg; idx<end; ++idx){
    int e = dperm[idx];
    int s = ei[e];
    float sc = AS[s] + adn; sc = sc>0.f ? sc : 0.2f*sc;
    float wgt = expf(sc-mx);
    acc += wgt * HG[(size_t)s*64+lane];
  }
  X2[(size_t)n*64+lane] = relu(acc/denom + GB[lane]);
}

// ---------------- mean-pool per graph + 3-layer MLP head ----------------
__global__ __launch_bounds__(64) void k_head(const float* __restrict__ X2,
      const int* __restrict__ batch,
      const float* __restrict__ F1W, const float* __restrict__ F1B,
      const float* __restrict__ F2W, const float* __restrict__ F2B,
      const float* __restrict__ F3W, const float* __restrict__ F3B,
      float* __restrict__ OUT){
  int lane = threadIdx.x;
  int g = blockIdx.x;
  int lo=0, hi=NN;
  while (lo<hi){ int m=(lo+hi)>>1; if (batch[m] < g) lo=m+1; else hi=m; }
  int start = lo;
  lo=0; hi=NN;
  while (lo<hi){ int m=(lo+hi)>>1; if (batch[m] < g+1) lo=m+1; else hi=m; }
  int stop = lo;
  float s = 0.f;
  for (int r=start; r<stop; ++r) s += X2[(size_t)r*64+lane];
  float cnt = (float)(stop-start);
  float mean = s / fmaxf(cnt, 1.f);
  float a0=F1B[lane], a1=F1B[64+lane];
  #pragma unroll
  for (int i=0;i<64;++i){
    float mv = rdlane(mean, i);
    a0 += mv*F1W[i*128+lane];
    a1 += mv*F1W[i*128+64+lane];
  }
  float g1a = relu(a0), g1b = relu(a1);
  float b = F2B[lane];
  #pragma unroll
  for (int k=0;k<64;++k){
    b += rdlane(g1a,k)*F2W[k*64+lane];
  }
  #pragma unroll
  for (int k=0;k<64;++k){
    b += rdlane(g1b,k)*F2W[(64+k)*64+lane];
  }
  float g2v = relu(b);
  float cc = (lane<32) ? F3B[lane] : 0.f;
  #pragma unroll
  for (int k=0;k<64;++k){
    cc += rdlane(g2v,k)*F3W[k*32+(lane&31)];
  }
  if (lane < 32) OUT[g*32+lane] = relu(cc);
}

extern "C" void kernel_launch(void* const* d_in, const int* in_sizes, int n_in,
                              void* d_out, int out_size, void* d_ws, size_t ws_size,
                              hipStream_t stream){
  const float* X   = (const float*)d_in[0];
  const float* EA  = (const float*)d_in[1];
  const float* W1  = (const float*)d_in[2];
  const float* B1  = (const float*)d_in[3];
  const float* W2  = (const float*)d_in[4];
  const float* B2  = (const float*)d_in[5];
  const float* W3  = (const float*)d_in[6];
  const float* B3  = (const float*)d_in[7];
  const float* RW  = (const float*)d_in[8];
  const float* CB  = (const float*)d_in[9];
  const float* GW  = (const float*)d_in[10];
  const float* ASRC= (const float*)d_in[11];
  const float* ADST= (const float*)d_in[12];
  const float* GB  = (const float*)d_in[13];
  const float* F1W = (const float*)d_in[14];
  const float* F1B = (const float*)d_in[15];
  const float* F2W = (const float*)d_in[16];
  const float* F2B = (const float*)d_in[17];
  const float* F3W = (const float*)d_in[18];
  const float* F3B = (const float*)d_in[19];
  const int*   EI  = (const int*)d_in[20];
  const int*   BATCH = (const int*)d_in[21];
  float* OUT = (float*)d_out;
  (void)in_sizes; (void)n_in; (void)out_size; (void)ws_size;

  char* w = (char*)d_ws;
  size_t off = 0;
  auto alloc = [&](size_t bytes)->char*{
    char* p = w + off; off = (off + bytes + 255) & ~(size_t)255; return p;
  };
  float* P    = (float*)alloc((size_t)NN*4096*4);   // 134 MB
  float* H1v  = (float*)alloc((size_t)NE*128*4);    // 67 MB
  float* H2v  = (float*)alloc((size_t)NE*64*4);     // 33.5 MB
  float* XB   = (float*)alloc((size_t)NN*64*4);
  float* AGG  = (float*)alloc((size_t)NN*64*4);
  float* HGv  = (float*)alloc((size_t)NN*64*4);
  float* X2   = (float*)alloc((size_t)NN*64*4);
  float* AS   = (float*)alloc((size_t)NN*4);
  float* AD   = (float*)alloc((size_t)NN*4);
  int* scnt = (int*)alloc((size_t)NN*4);
  int* dcnt = (int*)alloc((size_t)NN*4);
  int* soff = (int*)alloc((size_t)(NN+1)*4);
  int* doff = (int*)alloc((size_t)(NN+1)*4);
  int* scur = (int*)alloc((size_t)NN*4);
  int* dcur = (int*)alloc((size_t)NN*4);
  int* sperm= (int*)alloc((size_t)NE*4);
  int* dperm= (int*)alloc((size_t)NE*4);

  hipMemsetAsync(scnt, 0, NN*4, stream);
  hipMemsetAsync(dcnt, 0, NN*4, stream);
  k_hist<<<NE/256,256,0,stream>>>(EI, scnt, dcnt);
  k_scan<<<2,1024,0,stream>>>(scnt,dcnt,soff,scur,doff,dcur);
  k_scatter<<<NE/256,256,0,stream>>>(EI,scur,dcur,sperm,dperm);
  k_mlp1<<<NE/128,256,0,stream>>>(EA,W1,B1,H1v);
  k_mlp2<<<NE/128,256,0,stream>>>(H1v,W2,B2,H2v);
  k_pgen<<<NN/8,512,0,stream>>>(X,W3,P);
  k_root<<<NN/4,256,0,stream>>>(X,RW,CB,B3,AGG,XB);
  k_msg<<<NN,64,0,stream>>>(P,H2v,XB,EI,soff,sperm,AGG);
  k_hg<<<NN/4,256,0,stream>>>(AGG,GW,ASRC,ADST,HGv,AS,AD);
  k_gat<<<NN,64,0,stream>>>(HGv,AS,AD,GB,EI,doff,dperm,X2);
  k_head<<<NG,64,0,stream>>>(X2,BATCH,F1W,F1B,F2W,F2B,F3W,F3B,OUT);
}

// Round 8
// 459.361 us; speedup vs baseline: 2.1984x; 1.0950x over previous
//
#include <hip/hip_runtime.h>
#include <math.h>

#define NN 8192
#define NE 131072
#define NG 64
#define FIN 64
#define FE 32

static __device__ __forceinline__ float relu(float v){ return v > 0.f ? v : 0.f; }

static __device__ __forceinline__ float rdlane(float v, int l){
  return __int_as_float(__builtin_amdgcn_readlane(__float_as_int(v), l));
}

// ---------------- counting sorts (src and dst CSR) ----------------
__global__ void k_hist(const int* __restrict__ ei, int* scnt, int* dcnt){
  int e = blockIdx.x*256 + threadIdx.x;
  if (e < NE){ atomicAdd(&scnt[ei[e]],1); atomicAdd(&dcnt[ei[NE+e]],1); }
}

__global__ void k_scan(const int* __restrict__ scnt, const int* __restrict__ dcnt,
                       int* soff, int* scur, int* doff, int* dcur){
  const int* cnt = (blockIdx.x==0) ? scnt : dcnt;
  int* off = (blockIdx.x==0) ? soff : doff;
  int* cur = (blockIdx.x==0) ? scur : dcur;
  __shared__ int sums[1024];
  int t = threadIdx.x;
  int v[8]; int s = 0;
  #pragma unroll
  for (int j=0;j<8;++j){ v[j]=cnt[t*8+j]; s+=v[j]; }
  sums[t]=s; __syncthreads();
  for (int d=1; d<1024; d<<=1){
    int val = (t>=d) ? sums[t-d] : 0;
    __syncthreads();
    sums[t] += val;
    __syncthreads();
  }
  int run = sums[t]-s;   // exclusive prefix
  #pragma unroll
  for (int j=0;j<8;++j){ off[t*8+j]=run; cur[t*8+j]=run; run+=v[j]; }
  if (t==1023) off[NN]=run;
}

__global__ void k_scatter(const int* __restrict__ ei, int* scur, int* dcur,
                          int* sperm, int* dperm){
  int e = blockIdx.x*256 + threadIdx.x;
  if (e < NE){
    int s = ei[e], d = ei[NE+e];
    sperm[atomicAdd(&scur[s],1)] = e;
    dperm[atomicAdd(&dcur[d],1)] = e;
  }
}

// ---------------- EdgeMLP layer 1: H1T = relu(EA @ W1 + b1)^T  [128][E] ----------------
// lane = edge. Weight indices wave-uniform -> s_load -> SGPR operand of v_fmac
// (1 VALU op per MAC). EA read strided (L1 absorbs); H1T written coalesced.
__global__ __launch_bounds__(256,2) void k_mlp1(const float* __restrict__ EA,
      const float* __restrict__ W1, const float* __restrict__ B1,
      float* __restrict__ H1T){
  int tid=threadIdx.x, wv=tid>>6, lane=tid&63;
  int e = (blockIdx.x*4+wv)*64 + lane;
  float ea[32];
  const float4* eap = (const float4*)(EA + (size_t)e*32);
  #pragma unroll
  for (int q=0;q<8;++q){
    float4 v = eap[q];
    ea[4*q+0]=v.x; ea[4*q+1]=v.y; ea[4*q+2]=v.z; ea[4*q+3]=v.w;
  }
  #pragma unroll 1
  for (int c=0;c<8;++c){
    float h[16];
    #pragma unroll
    for (int j=0;j<16;++j) h[j]=B1[c*16+j];
    #pragma unroll
    for (int i=0;i<32;++i){
      #pragma unroll
      for (int j=0;j<16;++j) h[j] += ea[i]*W1[i*128 + c*16 + j];
    }
    #pragma unroll
    for (int j=0;j<16;++j) H1T[(size_t)(c*16+j)*NE + e] = relu(h[j]);
  }
}

// ---------------- EdgeMLP layer 2: H2 = relu(H1 @ W2 + b2)  [E,64] ----------------
// lane = edge. H1T read coalesced per k; W2 via SGPR operand (1 op/MAC);
// acc[64] in regs; LDS 64x65 per-wave transpose for coalesced [E][64] store.
__global__ __launch_bounds__(256,2) void k_mlp2(const float* __restrict__ H1T,
      const float* __restrict__ W2, const float* __restrict__ B2,
      float* __restrict__ H2out){
  __shared__ float xpose[4][64*65];
  int tid=threadIdx.x, wv=tid>>6, lane=tid&63;
  int e0 = (blockIdx.x*4+wv)*64;
  int e  = e0 + lane;
  float acc[64];
  #pragma unroll
  for (int o=0;o<64;++o) acc[o]=B2[o];
  #pragma unroll 2
  for (int k=0;k<128;++k){
    float hk = H1T[(size_t)k*NE + e];
    #pragma unroll
    for (int o=0;o<64;++o) acc[o] += hk*W2[k*64+o];
  }
  float* lds = &xpose[wv][0];
  #pragma unroll
  for (int o=0;o<64;++o) lds[lane*65+o] = relu(acc[o]);
  __syncthreads();
  #pragma unroll
  for (int q=0;q<64;++q)
    H2out[(size_t)(e0+q)*64 + lane] = lds[q*65+lane];
}

// ---------------- P[n,k,o] = sum_i x[n,i] * W3[k, i*64+o] ----------------
// lane=o; x via readlane stash; W3 streamed coalesced from L2; acc in regs.
__global__ __launch_bounds__(512,4) void k_pgen(const float* __restrict__ X,
      const float* __restrict__ W3, float* __restrict__ P){
  int tid = threadIdx.x;
  int kk = tid>>6, lane = tid&63;
  int n0 = blockIdx.x*8;
  float xv[8];
  #pragma unroll
  for (int n=0;n<8;++n) xv[n] = X[(size_t)(n0+n)*64 + lane];
  float acc[8][8];
  #pragma unroll
  for (int n=0;n<8;++n)
    #pragma unroll
    for (int j=0;j<8;++j) acc[n][j]=0.f;
  const float* wb = W3 + (size_t)(kk*8)*4096 + lane;
  #pragma unroll 4
  for (int i=0;i<64;++i){
    float w[8];
    #pragma unroll
    for (int j=0;j<8;++j) w[j] = wb[(size_t)j*4096 + i*64];
    float sx[8];
    #pragma unroll
    for (int n=0;n<8;++n) sx[n] = rdlane(xv[n], i);
    #pragma unroll
    for (int n=0;n<8;++n)
      #pragma unroll
      for (int j=0;j<8;++j) acc[n][j] += sx[n]*w[j];
  }
  float* pb = P + (size_t)n0*4096 + (size_t)kk*8*64 + lane;
  #pragma unroll
  for (int n=0;n<8;++n)
    #pragma unroll
    for (int j=0;j<8;++j)
      pb[(size_t)n*4096 + j*64] = acc[n][j];
}

// ---------------- agg init = x @ root_w + conv1_b ; xb = x @ b3mat ----------------
__global__ __launch_bounds__(256) void k_root(const float* __restrict__ X,
      const float* __restrict__ RW, const float* __restrict__ CB,
      const float* __restrict__ B3, float* __restrict__ AGG, float* __restrict__ XB){
  int tid=threadIdx.x, wv=tid>>6, lane=tid&63;
  int n = blockIdx.x*4 + wv;
  float xr = X[(size_t)n*64+lane];
  float aA = CB[lane], aB = 0.f;
  #pragma unroll
  for (int i=0;i<64;++i){
    float sx = rdlane(xr, i);
    aA += sx*RW[i*64+lane];
    aB += sx*B3[i*64+lane];
  }
  AGG[(size_t)n*64+lane]=aA; XB[(size_t)n*64+lane]=aB;
}

// ---------------- msg[e] = h2[e] @ P[src] + xb[src]; scatter-add to agg[dst] ----------------
// P row in VGPRs; h2 row is WAVE-UNIFORM (one src per block) -> scalar loads
// feeding v_fmac's SGPR slot: 1 VALU op per MAC, no rdlane.
__global__ __launch_bounds__(64) void k_msg(const float* __restrict__ P,
      const float* __restrict__ H2v, const float* __restrict__ XB,
      const int* __restrict__ ei, const int* __restrict__ soff,
      const int* __restrict__ sperm, float* __restrict__ AGG){
  int lane = threadIdx.x;
  int n = blockIdx.x;
  int beg = soff[n], end = soff[n+1];
  if (beg==end) return;
  float pr[64];
  const float* pb = P + (size_t)n*4096 + lane;
  #pragma unroll
  for (int k=0;k<64;++k) pr[k] = pb[k*64];
  float xbv = XB[(size_t)n*64+lane];
  #pragma unroll 1
  for (int idx=beg; idx<end; ++idx){
    int e = __builtin_amdgcn_readfirstlane(sperm[idx]);
    int d = __builtin_amdgcn_readfirstlane(ei[NE+e]);
    const float* h2 = H2v + (size_t)e*64;
    float acc = xbv;
    #pragma unroll
    for (int k=0;k<64;++k) acc += h2[k]*pr[k];
    atomicAdd(&AGG[(size_t)d*64+lane], acc);
  }
}

// ---------------- hg = relu(agg) @ gat_w ; per-node attn scalars ----------------
__global__ __launch_bounds__(256) void k_hg(const float* __restrict__ AGG,
      const float* __restrict__ GW, const float* __restrict__ ASRC,
      const float* __restrict__ ADST, float* __restrict__ HG,
      float* __restrict__ AS, float* __restrict__ AD){
  int tid=threadIdx.x, wv=tid>>6, lane=tid&63;
  int n = blockIdx.x*4+wv;
  float xr = relu(AGG[(size_t)n*64+lane]);
  float acc=0.f;
  #pragma unroll
  for (int i=0;i<64;++i){
    acc += rdlane(xr,i)*GW[i*64+lane];
  }
  HG[(size_t)n*64+lane]=acc;
  float t1 = acc*ASRC[lane], t2 = acc*ADST[lane];
  #pragma unroll
  for (int d=32; d>=1; d>>=1){ t1 += __shfl_xor(t1,d); t2 += __shfl_xor(t2,d); }
  if (lane==0){ AS[n]=t1; AD[n]=t2; }
}

// ---------------- GAT softmax + aggregate per dst node (incl self-loop) ----------------
__global__ __launch_bounds__(64) void k_gat(const float* __restrict__ HG,
      const float* __restrict__ AS, const float* __restrict__ AD,
      const float* __restrict__ GB, const int* __restrict__ ei,
      const int* __restrict__ doff, const int* __restrict__ dperm,
      float* __restrict__ X2){
  int lane = threadIdx.x;
  int n = blockIdx.x;
  int beg = doff[n], end = doff[n+1], deg = end-beg;
  float adn = AD[n];
  float selfsc = AS[n] + adn; selfsc = selfsc>0.f ? selfsc : 0.2f*selfsc;
  float lmax = -3.4e38f;
  for (int j=lane; j<deg; j+=64){
    int e = dperm[beg+j];
    float sc = AS[ei[e]] + adn; sc = sc>0.f ? sc : 0.2f*sc;
    lmax = fmaxf(lmax, sc);
  }
  #pragma unroll
  for (int d=32; d>=1; d>>=1) lmax = fmaxf(lmax, __shfl_xor(lmax,d));
  float mx = fmaxf(lmax, selfsc);
  float lsum = 0.f;
  for (int j=lane; j<deg; j+=64){
    int e = dperm[beg+j];
    float sc = AS[ei[e]] + adn; sc = sc>0.f ? sc : 0.2f*sc;
    lsum += expf(sc-mx);
  }
  #pragma unroll
  for (int d=32; d>=1; d>>=1) lsum += __shfl_xor(lsum,d);
  float wself = expf(selfsc-mx);
  float denom = lsum + wself;
  float acc = wself * HG[(size_t)n*64+lane];
  for (int idx=beg; idx<end; ++idx){
    int e = dperm[idx];
    int s = ei[e];
    float sc = AS[s] + adn; sc = sc>0.f ? sc : 0.2f*sc;
    float wgt = expf(sc-mx);
    acc += wgt * HG[(size_t)s*64+lane];
  }
  X2[(size_t)n*64+lane] = relu(acc/denom + GB[lane]);
}

// ---------------- mean-pool per graph + 3-layer MLP head ----------------
__global__ __launch_bounds__(64) void k_head(const float* __restrict__ X2,
      const int* __restrict__ batch,
      const float* __restrict__ F1W, const float* __restrict__ F1B,
      const float* __restrict__ F2W, const float* __restrict__ F2B,
      const float* __restrict__ F3W, const float* __restrict__ F3B,
      float* __restrict__ OUT){
  int lane = threadIdx.x;
  int g = blockIdx.x;
  int lo=0, hi=NN;
  while (lo<hi){ int m=(lo+hi)>>1; if (batch[m] < g) lo=m+1; else hi=m; }
  int start = lo;
  lo=0; hi=NN;
  while (lo<hi){ int m=(lo+hi)>>1; if (batch[m] < g+1) lo=m+1; else hi=m; }
  int stop = lo;
  float s = 0.f;
  for (int r=start; r<stop; ++r) s += X2[(size_t)r*64+lane];
  float cnt = (float)(stop-start);
  float mean = s / fmaxf(cnt, 1.f);
  float a0=F1B[lane], a1=F1B[64+lane];
  #pragma unroll
  for (int i=0;i<64;++i){
    float mv = rdlane(mean, i);
    a0 += mv*F1W[i*128+lane];
    a1 += mv*F1W[i*128+64+lane];
  }
  float g1a = relu(a0), g1b = relu(a1);
  float b = F2B[lane];
  #pragma unroll
  for (int k=0;k<64;++k){
    b += rdlane(g1a,k)*F2W[k*64+lane];
  }
  #pragma unroll
  for (int k=0;k<64;++k){
    b += rdlane(g1b,k)*F2W[(64+k)*64+lane];
  }
  float g2v = relu(b);
  float cc = (lane<32) ? F3B[lane] : 0.f;
  #pragma unroll
  for (int k=0;k<64;++k){
    cc += rdlane(g2v,k)*F3W[k*32+(lane&31)];
  }
  if (lane < 32) OUT[g*32+lane] = relu(cc);
}

extern "C" void kernel_launch(void* const* d_in, const int* in_sizes, int n_in,
                              void* d_out, int out_size, void* d_ws, size_t ws_size,
                              hipStream_t stream){
  const float* X   = (const float*)d_in[0];
  const float* EA  = (const float*)d_in[1];
  const float* W1  = (const float*)d_in[2];
  const float* B1  = (const float*)d_in[3];
  const float* W2  = (const float*)d_in[4];
  const float* B2  = (const float*)d_in[5];
  const float* W3  = (const float*)d_in[6];
  const float* B3  = (const float*)d_in[7];
  const float* RW  = (const float*)d_in[8];
  const float* CB  = (const float*)d_in[9];
  const float* GW  = (const float*)d_in[10];
  const float* ASRC= (const float*)d_in[11];
  const float* ADST= (const float*)d_in[12];
  const float* GB  = (const float*)d_in[13];
  const float* F1W = (const float*)d_in[14];
  const float* F1B = (const float*)d_in[15];
  const float* F2W = (const float*)d_in[16];
  const float* F2B = (const float*)d_in[17];
  const float* F3W = (const float*)d_in[18];
  const float* F3B = (const float*)d_in[19];
  const int*   EI  = (const int*)d_in[20];
  const int*   BATCH = (const int*)d_in[21];
  float* OUT = (float*)d_out;
  (void)in_sizes; (void)n_in; (void)out_size; (void)ws_size;

  char* w = (char*)d_ws;
  size_t off = 0;
  auto alloc = [&](size_t bytes)->char*{
    char* p = w + off; off = (off + bytes + 255) & ~(size_t)255; return p;
  };
  float* P    = (float*)alloc((size_t)NN*4096*4);   // 134 MB
  float* H1T  = (float*)alloc((size_t)NE*128*4);    // 67 MB (transposed [128][E])
  float* H2v  = (float*)alloc((size_t)NE*64*4);     // 33.5 MB
  float* XB   = (float*)alloc((size_t)NN*64*4);
  float* AGG  = (float*)alloc((size_t)NN*64*4);
  float* HGv  = (float*)alloc((size_t)NN*64*4);
  float* X2   = (float*)alloc((size_t)NN*64*4);
  float* AS   = (float*)alloc((size_t)NN*4);
  float* AD   = (float*)alloc((size_t)NN*4);
  int* scnt = (int*)alloc((size_t)NN*4);
  int* dcnt = (int*)alloc((size_t)NN*4);
  int* soff = (int*)alloc((size_t)(NN+1)*4);
  int* doff = (int*)alloc((size_t)(NN+1)*4);
  int* scur = (int*)alloc((size_t)NN*4);
  int* dcur = (int*)alloc((size_t)NN*4);
  int* sperm= (int*)alloc((size_t)NE*4);
  int* dperm= (int*)alloc((size_t)NE*4);

  hipMemsetAsync(scnt, 0, NN*4, stream);
  hipMemsetAsync(dcnt, 0, NN*4, stream);
  k_hist<<<NE/256,256,0,stream>>>(EI, scnt, dcnt);
  k_scan<<<2,1024,0,stream>>>(scnt,dcnt,soff,scur,doff,dcur);
  k_scatter<<<NE/256,256,0,stream>>>(EI,scur,dcur,sperm,dperm);
  k_mlp1<<<NE/256,256,0,stream>>>(EA,W1,B1,H1T);
  k_mlp2<<<NE/256,256,0,stream>>>(H1T,W2,B2,H2v);
  k_pgen<<<NN/8,512,0,stream>>>(X,W3,P);
  k_root<<<NN/4,256,0,stream>>>(X,RW,CB,B3,AGG,XB);
  k_msg<<<NN,64,0,stream>>>(P,H2v,XB,EI,soff,sperm,AGG);
  k_hg<<<NN/4,256,0,stream>>>(AGG,GW,ASRC,ADST,HGv,AS,AD);
  k_gat<<<NN,64,0,stream>>>(HGv,AS,AD,GB,EI,doff,dperm,X2);
  k_head<<<NG,64,0,stream>>>(X2,BATCH,F1W,F1B,F2W,F2B,F3W,F3B,OUT);
}

// Round 12
// 455.409 us; speedup vs baseline: 2.2175x; 1.0087x over previous
//
#include <hip/hip_runtime.h>
#include <math.h>

#define NN 8192
#define NE 131072
#define NG 64
#define FIN 64
#define FE 32

static __device__ __forceinline__ float relu(float v){ return v > 0.f ? v : 0.f; }

static __device__ __forceinline__ float rdlane(float v, int l){
  return __int_as_float(__builtin_amdgcn_readlane(__float_as_int(v), l));
}

#define E16(M) M(0) M(1) M(2) M(3) M(4) M(5) M(6) M(7) M(8) M(9) M(10) M(11) M(12) M(13) M(14) M(15)

// ---------------- counting sorts (src and dst CSR) ----------------
__global__ void k_hist(const int* __restrict__ ei, int* scnt, int* dcnt){
  int e = blockIdx.x*256 + threadIdx.x;
  if (e < NE){ atomicAdd(&scnt[ei[e]],1); atomicAdd(&dcnt[ei[NE+e]],1); }
}

__global__ void k_scan(const int* __restrict__ scnt, const int* __restrict__ dcnt,
                       int* soff, int* scur, int* doff, int* dcur){
  const int* cnt = (blockIdx.x==0) ? scnt : dcnt;
  int* off = (blockIdx.x==0) ? soff : doff;
  int* cur = (blockIdx.x==0) ? scur : dcur;
  __shared__ int sums[1024];
  int t = threadIdx.x;
  int v[8]; int s = 0;
  #pragma unroll
  for (int j=0;j<8;++j){ v[j]=cnt[t*8+j]; s+=v[j]; }
  sums[t]=s; __syncthreads();
  for (int d=1; d<1024; d<<=1){
    int val = (t>=d) ? sums[t-d] : 0;
    __syncthreads();
    sums[t] += val;
    __syncthreads();
  }
  int run = sums[t]-s;   // exclusive prefix
  #pragma unroll
  for (int j=0;j<8;++j){ off[t*8+j]=run; cur[t*8+j]=run; run+=v[j]; }
  if (t==1023) off[NN]=run;
}

__global__ void k_scatter(const int* __restrict__ ei, int* scur, int* dcur,
                          int* sperm, int* dperm){
  int e = blockIdx.x*256 + threadIdx.x;
  if (e < NE){
    int s = ei[e], d = ei[NE+e];
    sperm[atomicAdd(&scur[s],1)] = e;
    dperm[atomicAdd(&dcur[d],1)] = e;
  }
}

// ---------------- EdgeMLP layer 1: H1 = relu(EA @ W1 + b1)  [E,128] ----------------
// lane owns cols (lane, lane+64); W1 col pair in 64 VGPRs; edge feats stashed
// 4 regs/lane; i-loop FULLY unrolled (all indices compile-time; 1 rdlane -> 2 fmac).
__global__ __launch_bounds__(256,2) void k_mlp1(const float* __restrict__ EA,
      const float* __restrict__ W1, const float* __restrict__ B1,
      float* __restrict__ H1out){
  int tid=threadIdx.x, wv=tid>>6, lane=tid&63;
  float w1a[32], w1b[32];
  #pragma unroll
  for (int i=0;i<32;++i){ w1a[i]=W1[i*128+lane]; w1b[i]=W1[i*128+64+lane]; }
  float b1a=B1[lane], b1b=B1[64+lane];
  int e0 = (blockIdx.x*4 + wv)*16;
  #pragma unroll 1
  for (int t=0;t<2;++t){
    int eb = e0 + t*8;
    float r0 = EA[(size_t)eb*32 +   0 + lane];
    float r1 = EA[(size_t)eb*32 +  64 + lane];
    float r2 = EA[(size_t)eb*32 + 128 + lane];
    float r3 = EA[(size_t)eb*32 + 192 + lane];
    float acc0[8], acc1[8];
    #pragma unroll
    for (int e=0;e<8;++e){ acc0[e]=b1a; acc1[e]=b1b; }
    #pragma unroll
    for (int i=0;i<32;++i){
      #pragma unroll
      for (int e=0;e<8;++e){
        float src = (e<2)?r0 : (e<4)?r1 : (e<6)?r2 : r3;
        float sx = rdlane(src, (e&1)*32 + i);
        acc0[e] += sx*w1a[i];
        acc1[e] += sx*w1b[i];
      }
    }
    #pragma unroll
    for (int e=0;e<8;++e){
      H1out[(size_t)(eb+e)*128 + lane]      = relu(acc0[e]);
      H1out[(size_t)(eb+e)*128 + 64 + lane] = relu(acc1[e]);
    }
  }
}

// ---------------- EdgeMLP layer 2: H2 = relu(H1 @ W2 + b2)  [E,64] ----------------
// lane = col o. 16 edges/wave; h-stash and acc as NAMED scalars (cannot be
// demoted to scratch); W2 streamed as one coalesced vload per k.
__global__ __launch_bounds__(256,2) void k_mlp2(const float* __restrict__ H1v,
      const float* __restrict__ W2, const float* __restrict__ B2,
      float* __restrict__ H2out){
  int tid=threadIdx.x, wv=tid>>6, lane=tid&63;
  float b2v = B2[lane];
  int e0 = (blockIdx.x*4 + wv)*16;
  const float* hb = H1v + (size_t)e0*128 + lane;
  #define DECLH(e) float h0_##e = hb[e*128]; float h1_##e = hb[e*128+64];
  E16(DECLH)
  #undef DECLH
  #define DECLA(e) float a_##e = b2v;
  E16(DECLA)
  #undef DECLA
  const float* w2p = W2 + lane;
  #pragma unroll 4
  for (int k=0;k<64;++k){
    float wk = w2p[k*64];
    #define MAC0(e) a_##e += rdlane(h0_##e, k)*wk;
    E16(MAC0)
    #undef MAC0
  }
  #pragma unroll 4
  for (int k=0;k<64;++k){
    float wk = w2p[(64+k)*64];
    #define MAC1(e) a_##e += rdlane(h1_##e, k)*wk;
    E16(MAC1)
    #undef MAC1
  }
  #define STOREH2(e) H2out[(size_t)(e0+e)*64 + lane] = relu(a_##e);
  E16(STOREH2)
  #undef STOREH2
}

// ---------------- P[n,k,o] = sum_i x[n,i] * W3[k, i*64+o] ----------------
// lane=o; x via readlane stash; W3 streamed coalesced from L2; acc in regs.
__global__ __launch_bounds__(512,4) void k_pgen(const float* __restrict__ X,
      const float* __restrict__ W3, float* __restrict__ P){
  int tid = threadIdx.x;
  int kk = tid>>6, lane = tid&63;
  int n0 = blockIdx.x*8;
  float xv[8];
  #pragma unroll
  for (int n=0;n<8;++n) xv[n] = X[(size_t)(n0+n)*64 + lane];
  float acc[8][8];
  #pragma unroll
  for (int n=0;n<8;++n)
    #pragma unroll
    for (int j=0;j<8;++j) acc[n][j]=0.f;
  const float* wb = W3 + (size_t)(kk*8)*4096 + lane;
  #pragma unroll 4
  for (int i=0;i<64;++i){
    float w[8];
    #pragma unroll
    for (int j=0;j<8;++j) w[j] = wb[(size_t)j*4096 + i*64];
    float sx[8];
    #pragma unroll
    for (int n=0;n<8;++n) sx[n] = rdlane(xv[n], i);
    #pragma unroll
    for (int n=0;n<8;++n)
      #pragma unroll
      for (int j=0;j<8;++j) acc[n][j] += sx[n]*w[j];
  }
  float* pb = P + (size_t)n0*4096 + (size_t)kk*8*64 + lane;
  #pragma unroll
  for (int n=0;n<8;++n)
    #pragma unroll
    for (int j=0;j<8;++j)
      pb[(size_t)n*4096 + j*64] = acc[n][j];
}

// ---------------- agg init = x @ root_w + conv1_b ; xb = x @ b3mat ----------------
__global__ __launch_bounds__(256) void k_root(const float* __restrict__ X,
      const float* __restrict__ RW, const float* __restrict__ CB,
      const float* __restrict__ B3, float* __restrict__ AGG, float* __restrict__ XB){
  int tid=threadIdx.x, wv=tid>>6, lane=tid&63;
  int n = blockIdx.x*4 + wv;
  float xr = X[(size_t)n*64+lane];
  float aA = CB[lane], aB = 0.f;
  #pragma unroll
  for (int i=0;i<64;++i){
    float sx = rdlane(xr, i);
    aA += sx*RW[i*64+lane];
    aB += sx*B3[i*64+lane];
  }
  AGG[(size_t)n*64+lane]=aA; XB[(size_t)n*64+lane]=aB;
}

// ---------------- msg[e] = h2[e] @ P[src] + xb[src]; scatter-add to agg[dst] ----------------
// P row in VGPRs; h2 row is WAVE-UNIFORM (one src per block) -> scalar loads
// feeding v_fmac's SGPR slot: 1 VALU op per MAC, no rdlane.
__global__ __launch_bounds__(64) void k_msg(const float* __restrict__ P,
      const float* __restrict__ H2v, const float* __restrict__ XB,
      const int* __restrict__ ei, const int* __restrict__ soff,
      const int* __restrict__ sperm, float* __restrict__ AGG){
  int lane = threadIdx.x;
  int n = blockIdx.x;
  int beg = soff[n], end = soff[n+1];
  if (beg==end) return;
  float pr[64];
  const float* pb = P + (size_t)n*4096 + lane;
  #pragma unroll
  for (int k=0;k<64;++k) pr[k] = pb[k*64];
  float xbv = XB[(size_t)n*64+lane];
  #pragma unroll 1
  for (int idx=beg; idx<end; ++idx){
    int e = __builtin_amdgcn_readfirstlane(sperm[idx]);
    int d = __builtin_amdgcn_readfirstlane(ei[NE+e]);
    const float* h2 = H2v + (size_t)e*64;
    float acc = xbv;
    #pragma unroll
    for (int k=0;k<64;++k) acc += h2[k]*pr[k];
    atomicAdd(&AGG[(size_t)d*64+lane], acc);
  }
}

// ---------------- hg = relu(agg) @ gat_w ; per-node attn scalars ----------------
__global__ __launch_bounds__(256) void k_hg(const float* __restrict__ AGG,
      const float* __restrict__ GW, const float* __restrict__ ASRC,
      const float* __restrict__ ADST, float* __restrict__ HG,
      float* __restrict__ AS, float* __restrict__ AD){
  int tid=threadIdx.x, wv=tid>>6, lane=tid&63;
  int n = blockIdx.x*4+wv;
  float xr = relu(AGG[(size_t)n*64+lane]);
  float acc=0.f;
  #pragma unroll
  for (int i=0;i<64;++i){
    acc += rdlane(xr,i)*GW[i*64+lane];
  }
  HG[(size_t)n*64+lane]=acc;
  float t1 = acc*ASRC[lane], t2 = acc*ADST[lane];
  #pragma unroll
  for (int d=32; d>=1; d>>=1){ t1 += __shfl_xor(t1,d); t2 += __shfl_xor(t2,d); }
  if (lane==0){ AS[n]=t1; AD[n]=t2; }
}

// ---------------- GAT softmax + aggregate per dst node (incl self-loop) ----------------
__global__ __launch_bounds__(64) void k_gat(const float* __restrict__ HG,
      const float* __restrict__ AS, const float* __restrict__ AD,
      const float* __restrict__ GB, const int* __restrict__ ei,
      const int* __restrict__ doff, const int* __restrict__ dperm,
      float* __restrict__ X2){
  int lane = threadIdx.x;
  int n = blockIdx.x;
  int beg = doff[n], end = doff[n+1], deg = end-beg;
  float adn = AD[n];
  float selfsc = AS[n] + adn; selfsc = selfsc>0.f ? selfsc : 0.2f*selfsc;
  float lmax = -3.4e38f;
  for (int j=lane; j<deg; j+=64){
    int e = dperm[beg+j];
    float sc = AS[ei[e]] + adn; sc = sc>0.f ? sc : 0.2f*sc;
    lmax = fmaxf(lmax, sc);
  }
  #pragma unroll
  for (int d=32; d>=1; d>>=1) lmax = fmaxf(lmax, __shfl_xor(lmax,d));
  float mx = fmaxf(lmax, selfsc);
  float lsum = 0.f;
  for (int j=lane; j<deg; j+=64){
    int e = dperm[beg+j];
    float sc = AS[ei[e]] + adn; sc = sc>0.f ? sc : 0.2f*sc;
    lsum += expf(sc-mx);
  }
  #pragma unroll
  for (int d=32; d>=1; d>>=1) lsum += __shfl_xor(lsum,d);
  float wself = expf(selfsc-mx);
  float denom = lsum + wself;
  float acc = wself * HG[(size_t)n*64+lane];
  for (int idx=beg; idx<end; ++idx){
    int e = dperm[idx];
    int s = ei[e];
    float sc = AS[s] + adn; sc = sc>0.f ? sc : 0.2f*sc;
    float wgt = expf(sc-mx);
    acc += wgt * HG[(size_t)s*64+lane];
  }
  X2[(size_t)n*64+lane] = relu(acc/denom + GB[lane]);
}

// ---------------- mean-pool per graph + 3-layer MLP head ----------------
__global__ __launch_bounds__(64) void k_head(const float* __restrict__ X2,
      const int* __restrict__ batch,
      const float* __restrict__ F1W, const float* __restrict__ F1B,
      const float* __restrict__ F2W, const float* __restrict__ F2B,
      const float* __restrict__ F3W, const float* __restrict__ F3B,
      float* __restrict__ OUT){
  int lane = threadIdx.x;
  int g = blockIdx.x;
  int lo=0, hi=NN;
  while (lo<hi){ int m=(lo+hi)>>1; if (batch[m] < g) lo=m+1; else hi=m; }
  int start = lo;
  lo=0; hi=NN;
  while (lo<hi){ int m=(lo+hi)>>1; if (batch[m] < g+1) lo=m+1; else hi=m; }
  int stop = lo;
  float s = 0.f;
  for (int r=start; r<stop; ++r) s += X2[(size_t)r*64+lane];
  float cnt = (float)(stop-start);
  float mean = s / fmaxf(cnt, 1.f);
  float a0=F1B[lane], a1=F1B[64+lane];
  #pragma unroll
  for (int i=0;i<64;++i){
    float mv = rdlane(mean, i);
    a0 += mv*F1W[i*128+lane];
    a1 += mv*F1W[i*128+64+lane];
  }
  float g1a = relu(a0), g1b = relu(a1);
  float b = F2B[lane];
  #pragma unroll
  for (int k=0;k<64;++k){
    b += rdlane(g1a,k)*F2W[k*64+lane];
  }
  #pragma unroll
  for (int k=0;k<64;++k){
    b += rdlane(g1b,k)*F2W[(64+k)*64+lane];
  }
  float g2v = relu(b);
  float cc = (lane<32) ? F3B[lane] : 0.f;
  #pragma unroll
  for (int k=0;k<64;++k){
    cc += rdlane(g2v,k)*F3W[k*32+(lane&31)];
  }
  if (lane < 32) OUT[g*32+lane] = relu(cc);
}

extern "C" void kernel_launch(void* const* d_in, const int* in_sizes, int n_in,
                              void* d_out, int out_size, void* d_ws, size_t ws_size,
                              hipStream_t stream){
  const float* X   = (const float*)d_in[0];
  const float* EA  = (const float*)d_in[1];
  const float* W1  = (const float*)d_in[2];
  const float* B1  = (const float*)d_in[3];
  const float* W2  = (const float*)d_in[4];
  const float* B2  = (const float*)d_in[5];
  const float* W3  = (const float*)d_in[6];
  const float* B3  = (const float*)d_in[7];
  const float* RW  = (const float*)d_in[8];
  const float* CB  = (const float*)d_in[9];
  const float* GW  = (const float*)d_in[10];
  const float* ASRC= (const float*)d_in[11];
  const float* ADST= (const float*)d_in[12];
  const float* GB  = (const float*)d_in[13];
  const float* F1W = (const float*)d_in[14];
  const float* F1B = (const float*)d_in[15];
  const float* F2W = (const float*)d_in[16];
  const float* F2B = (const float*)d_in[17];
  const float* F3W = (const float*)d_in[18];
  const float* F3B = (const float*)d_in[19];
  const int*   EI  = (const int*)d_in[20];
  const int*   BATCH = (const int*)d_in[21];
  float* OUT = (float*)d_out;
  (void)in_sizes; (void)n_in; (void)out_size; (void)ws_size;

  char* w = (char*)d_ws;
  size_t off = 0;
  auto alloc = [&](size_t bytes)->char*{
    char* p = w + off; off = (off + bytes + 255) & ~(size_t)255; return p;
  };
  float* P    = (float*)alloc((size_t)NN*4096*4);   // 134 MB
  float* H1v  = (float*)alloc((size_t)NE*128*4);    // 67 MB [E][128]
  float* H2v  = (float*)alloc((size_t)NE*64*4);     // 33.5 MB
  float* XB   = (float*)alloc((size_t)NN*64*4);
  float* AGG  = (float*)alloc((size_t)NN*64*4);
  float* HGv  = (float*)alloc((size_t)NN*64*4);
  float* X2   = (float*)alloc((size_t)NN*64*4);
  float* AS   = (float*)alloc((size_t)NN*4);
  float* AD   = (float*)alloc((size_t)NN*4);
  int* scnt = (int*)alloc((size_t)NN*4);
  int* dcnt = (int*)alloc((size_t)NN*4);
  int* soff = (int*)alloc((size_t)(NN+1)*4);
  int* doff = (int*)alloc((size_t)(NN+1)*4);
  int* scur = (int*)alloc((size_t)NN*4);
  int* dcur = (int*)alloc((size_t)NN*4);
  int* sperm= (int*)alloc((size_t)NE*4);
  int* dperm= (int*)alloc((size_t)NE*4);

  hipMemsetAsync(scnt, 0, NN*4, stream);
  hipMemsetAsync(dcnt, 0, NN*4, stream);
  k_hist<<<NE/256,256,0,stream>>>(EI, scnt, dcnt);
  k_scan<<<2,1024,0,stream>>>(scnt,dcnt,soff,scur,doff,dcur);
  k_scatter<<<NE/256,256,0,stream>>>(EI,scur,dcur,sperm,dperm);
  k_mlp1<<<NE/64,256,0,stream>>>(EA,W1,B1,H1v);
  k_mlp2<<<NE/64,256,0,stream>>>(H1v,W2,B2,H2v);
  k_pgen<<<NN/8,512,0,stream>>>(X,W3,P);
  k_root<<<NN/4,256,0,stream>>>(X,RW,CB,B3,AGG,XB);
  k_msg<<<NN,64,0,stream>>>(P,H2v,XB,EI,soff,sperm,AGG);
  k_hg<<<NN/4,256,0,stream>>>(AGG,GW,ASRC,ADST,HGv,AS,AD);
  k_gat<<<NN,64,0,stream>>>(HGv,AS,AD,GB,EI,doff,dperm,X2);
  k_head<<<NG,64,0,stream>>>(X2,BATCH,F1W,F1B,F2W,F2B,F3W,F3B,OUT);
}